// Round 1
// baseline (492.637 us; speedup 1.0000x reference)
//
#include <hip/hip_runtime.h>

// Causal linear attention (Performer ReLU kernel), chunked-scan formulation.
// B=2 L=4096 H=8 D=64 M=256, fp32. Chunk T=128, C=32 chunks, NBH=16 heads.
// ws layout: S [NBH][C][M*D] (32 MB) then Z [NBH][C][M] (0.5 MB) = ~32.5 MiB.

#define B_   2
#define L_   4096
#define H_   8
#define D_   64
#define M_   256
#define T_   128
#define C_   (L_ / T_)   // 32
#define NBH  (B_ * H_)   // 16
#define TS   32          // LDS staging sub-tile (timesteps)
#define RATIO 0.0625f    // 1/sqrt(M)
#define STAB  0.001f

// ---------------- Phase 1: per-chunk K-feature sums ----------------
// block = (chunk c, head bh). Thread t owns feature m=t: proj row in regs,
// S row [D] in regs. k/v staged in LDS, rows read as broadcasts.
__global__ __launch_bounds__(256, 2)
void phase1_kernel(const float* __restrict__ key, const float* __restrict__ val,
                   const float* __restrict__ proj,
                   float* __restrict__ S, float* __restrict__ Z) {
    const int c = blockIdx.x, bh = blockIdx.y;
    const int b = bh / H_, h = bh % H_;
    const int tid = threadIdx.x;

    __shared__ float kT[TS * D_];
    __shared__ float vT[TS * D_];

    // proj row m = tid -> registers (one-time, L2-served)
    float preg[D_];
    {
        const float4* p4 = (const float4*)(proj + (size_t)tid * D_);
#pragma unroll
        for (int i = 0; i < D_ / 4; ++i) {
            float4 t = p4[i];
            preg[4*i] = t.x; preg[4*i+1] = t.y; preg[4*i+2] = t.z; preg[4*i+3] = t.w;
        }
    }

    float Sreg[D_];
#pragma unroll
    for (int i = 0; i < D_; ++i) Sreg[i] = 0.f;
    float zreg = 0.f;

    const size_t base = ((size_t)b * L_ + (size_t)c * T_) * (H_ * D_) + (size_t)h * D_;

    for (int t0 = 0; t0 < T_; t0 += TS) {
        __syncthreads();
        // stage k,v sub-tile: 512 float4 per array, 2 per thread
#pragma unroll
        for (int kk = 0; kk < 2; ++kk) {
            int idx4 = tid + kk * 256;
            int ls = idx4 >> 4;       // /16 float4 per row
            int dd = idx4 & 15;
            size_t g = base + (size_t)(t0 + ls) * (H_ * D_) + (size_t)dd * 4;
            float4 kv4 = *(const float4*)(key + g);
            float4 vv4 = *(const float4*)(val + g);
            *(float4*)(&kT[ls * D_ + dd * 4]) = kv4;
            *(float4*)(&vT[ls * D_ + dd * 4]) = vv4;
        }
        __syncthreads();

        for (int ls = 0; ls < TS; ++ls) {
            const float4* krow = (const float4*)(&kT[ls * D_]);
            float a0 = 0.f, a1 = 0.f, a2 = 0.f, a3 = 0.f;
#pragma unroll
            for (int i = 0; i < D_ / 4; ++i) {
                float4 kk4 = krow[i];
                a0 = fmaf(preg[4*i],   kk4.x, a0);
                a1 = fmaf(preg[4*i+1], kk4.y, a1);
                a2 = fmaf(preg[4*i+2], kk4.z, a2);
                a3 = fmaf(preg[4*i+3], kk4.w, a3);
            }
            float kp = fmaxf(RATIO * ((a0 + a1) + (a2 + a3)), 0.f) + STAB;
            zreg += kp;
            const float4* vrow = (const float4*)(&vT[ls * D_]);
#pragma unroll
            for (int i = 0; i < D_ / 4; ++i) {
                float4 vv4 = vrow[i];
                Sreg[4*i]   = fmaf(kp, vv4.x, Sreg[4*i]);
                Sreg[4*i+1] = fmaf(kp, vv4.y, Sreg[4*i+1]);
                Sreg[4*i+2] = fmaf(kp, vv4.z, Sreg[4*i+2]);
                Sreg[4*i+3] = fmaf(kp, vv4.w, Sreg[4*i+3]);
            }
        }
    }

    float* Sout = S + ((size_t)(bh * C_ + c)) * (M_ * D_) + (size_t)tid * D_;
#pragma unroll
    for (int d = 0; d < D_; d += 4) {
        float4 t; t.x = Sreg[d]; t.y = Sreg[d+1]; t.z = Sreg[d+2]; t.w = Sreg[d+3];
        *(float4*)(Sout + d) = t;
    }
    Z[(size_t)(bh * C_ + c) * M_ + tid] = zreg;
}

// ---------------- Phase 2: exclusive prefix over chunks (in place) --------
__global__ void phase2_kernel(float* __restrict__ S, float* __restrict__ Z) {
    const int bh = blockIdx.y;
    const int j = blockIdx.x * 256 + threadIdx.x;
    if (j < M_ * D_) {
        float run = 0.f;
        float* p = S + (size_t)bh * C_ * M_ * D_ + j;
        for (int c = 0; c < C_; ++c) {
            float t = p[(size_t)c * (M_ * D_)];
            p[(size_t)c * (M_ * D_)] = run;
            run += t;
        }
    } else {
        const int j2 = j - M_ * D_;
        if (j2 < M_) {
            float run = 0.f;
            float* p = Z + (size_t)bh * C_ * M_ + j2;
            for (int c = 0; c < C_; ++c) {
                float t = p[c * M_];
                p[c * M_] = run;
                run += t;
            }
        }
    }
}

// ---------------- Phase 3: within-chunk scan seeded from prefix ----------
// Wave w owns kv[m=64w+i][d=lane] (64 regs). Thread t owns feature m=t for
// the projections (proj row in regs) and z running-sum.
__global__ __launch_bounds__(256, 2)
void phase3_kernel(const float* __restrict__ q, const float* __restrict__ key,
                   const float* __restrict__ val, const float* __restrict__ proj,
                   const float* __restrict__ S, const float* __restrict__ Z,
                   float* __restrict__ out) {
    const int c = blockIdx.x, bh = blockIdx.y;
    const int b = bh / H_, h = bh % H_;
    const int tid = threadIdx.x;
    const int w = tid >> 6, lane = tid & 63;

    __shared__ float qT[TS * D_];
    __shared__ float kT[TS * D_];
    __shared__ float vT[TS * D_];
    __shared__ float qpS[M_];
    __shared__ float kpS[M_];
    __shared__ float red[M_];
    __shared__ float denS[4];

    float preg[D_];
    {
        const float4* p4 = (const float4*)(proj + (size_t)tid * D_);
#pragma unroll
        for (int i = 0; i < D_ / 4; ++i) {
            float4 t = p4[i];
            preg[4*i] = t.x; preg[4*i+1] = t.y; preg[4*i+2] = t.z; preg[4*i+3] = t.w;
        }
    }

    // seed kv state from exclusive prefix
    const float* Sp = S + (size_t)(bh * C_ + c) * (M_ * D_);
    float kv[D_];
#pragma unroll
    for (int i = 0; i < D_; ++i) kv[i] = Sp[(size_t)(64 * w + i) * D_ + lane];
    float zc = Z[(size_t)(bh * C_ + c) * M_ + tid];

    const size_t base = ((size_t)b * L_ + (size_t)c * T_) * (H_ * D_) + (size_t)h * D_;

    for (int t0 = 0; t0 < T_; t0 += TS) {
        __syncthreads();
#pragma unroll
        for (int kk = 0; kk < 2; ++kk) {
            int idx4 = tid + kk * 256;
            int ls = idx4 >> 4;
            int dd = idx4 & 15;
            size_t g = base + (size_t)(t0 + ls) * (H_ * D_) + (size_t)dd * 4;
            float4 q4 = *(const float4*)(q   + g);
            float4 k4 = *(const float4*)(key + g);
            float4 v4 = *(const float4*)(val + g);
            *(float4*)(&qT[ls * D_ + dd * 4]) = q4;
            *(float4*)(&kT[ls * D_ + dd * 4]) = k4;
            *(float4*)(&vT[ls * D_ + dd * 4]) = v4;
        }
        __syncthreads();

        for (int ls = 0; ls < TS; ++ls) {
            // projections for feature m=tid (broadcast LDS reads)
            const float4* qrow = (const float4*)(&qT[ls * D_]);
            const float4* krow = (const float4*)(&kT[ls * D_]);
            float qa0=0.f,qa1=0.f,qa2=0.f,qa3=0.f, ka0=0.f,ka1=0.f,ka2=0.f,ka3=0.f;
#pragma unroll
            for (int i = 0; i < D_ / 4; ++i) {
                float4 q4 = qrow[i]; float4 k4 = krow[i];
                qa0 = fmaf(preg[4*i],   q4.x, qa0); ka0 = fmaf(preg[4*i],   k4.x, ka0);
                qa1 = fmaf(preg[4*i+1], q4.y, qa1); ka1 = fmaf(preg[4*i+1], k4.y, ka1);
                qa2 = fmaf(preg[4*i+2], q4.z, qa2); ka2 = fmaf(preg[4*i+2], k4.z, ka2);
                qa3 = fmaf(preg[4*i+3], q4.w, qa3); ka3 = fmaf(preg[4*i+3], k4.w, ka3);
            }
            float qp = fmaxf(RATIO * ((qa0+qa1)+(qa2+qa3)), 0.f) + STAB;
            float kp = fmaxf(RATIO * ((ka0+ka1)+(ka2+ka3)), 0.f) + STAB;
            zc += kp;
            float denp = qp * zc;
            qpS[tid] = qp;
            kpS[tid] = kp;
            // wave-reduce den partial (64 lanes)
            denp += __shfl_xor(denp, 32, 64);
            denp += __shfl_xor(denp, 16, 64);
            denp += __shfl_xor(denp,  8, 64);
            denp += __shfl_xor(denp,  4, 64);
            denp += __shfl_xor(denp,  2, 64);
            denp += __shfl_xor(denp,  1, 64);
            __syncthreads();                 // qp/kp visible; prev readers done
            if (lane == 0) denS[w] = denp;

            // kv update + numerator partial for d=lane, m in [64w, 64w+64)
            float vreg = vT[ls * D_ + lane];
            const float4* kp4 = (const float4*)(&kpS[w * 64]);
            const float4* qp4 = (const float4*)(&qpS[w * 64]);
            float n0=0.f, n1=0.f, n2=0.f, n3=0.f;
#pragma unroll
            for (int i = 0; i < 16; ++i) {
                float4 kk4 = kp4[i]; float4 qq4 = qp4[i];
                kv[4*i]   = fmaf(kk4.x, vreg, kv[4*i]);   n0 = fmaf(qq4.x, kv[4*i],   n0);
                kv[4*i+1] = fmaf(kk4.y, vreg, kv[4*i+1]); n1 = fmaf(qq4.y, kv[4*i+1], n1);
                kv[4*i+2] = fmaf(kk4.z, vreg, kv[4*i+2]); n2 = fmaf(qq4.z, kv[4*i+2], n2);
                kv[4*i+3] = fmaf(kk4.w, vreg, kv[4*i+3]); n3 = fmaf(qq4.w, kv[4*i+3], n3);
            }
            red[tid] = (n0 + n1) + (n2 + n3);
            __syncthreads();

            if (tid < 64) {
                float num = red[tid] + red[64 + tid] + red[128 + tid] + red[192 + tid];
                float den = denS[0] + denS[1] + denS[2] + denS[3];
                if (den <= 0.f) den = 1.f;
                int l = c * T_ + t0 + ls;
                out[((size_t)(b * L_ + l) * H_ + h) * D_ + tid] = num / den;
            }
        }
    }
}

extern "C" void kernel_launch(void* const* d_in, const int* in_sizes, int n_in,
                              void* d_out, int out_size, void* d_ws, size_t ws_size,
                              hipStream_t stream) {
    const float* q    = (const float*)d_in[0];
    const float* k    = (const float*)d_in[1];
    const float* v    = (const float*)d_in[2];
    const float* proj = (const float*)d_in[3];
    float* out = (float*)d_out;

    float* S = (float*)d_ws;                       // NBH*C*M*D floats
    float* Z = S + (size_t)NBH * C_ * M_ * D_;     // NBH*C*M floats

    dim3 blk(256);
    dim3 g1(C_, NBH);
    phase1_kernel<<<g1, blk, 0, stream>>>(k, v, proj, S, Z);
    dim3 g2((M_ * D_ + M_) / 256, NBH);            // 65 x 16
    phase2_kernel<<<g2, blk, 0, stream>>>(S, Z);
    phase3_kernel<<<g1, blk, 0, stream>>>(q, k, v, proj, S, Z, out);
}